// Round 1
// baseline (501.535 us; speedup 1.0000x reference)
//
#include <hip/hip_runtime.h>
#include <hip/hip_bf16.h>

typedef __bf16 bf16_8 __attribute__((ext_vector_type(8)));
typedef float  f32_4  __attribute__((ext_vector_type(4)));

#define NNODES 50000
#define NEDGES 800000
#define INDIM  512
#define HIDDIM 256
#define CSTRIDE 264   // elems; 264*2=528 B rows (16B-aligned), breaks pow2 bank stride

// ---------------- small utility kernels ----------------

__global__ void zero_kernel(int* p, int n) {
    int i = blockIdx.x * 256 + threadIdx.x;
    if (i < n) p[i] = 0;
}

// flags[0]: edge_index is int64 (odd int32 words all zero)
// flags[1]: float data is bf16 (even halfwords of x look like sane bf16 exponents)
__global__ void detect_kernel(const int* __restrict__ ei,
                              const unsigned short* __restrict__ xh,
                              int* __restrict__ flags) {
    int t = threadIdx.x;                       // 64 threads
    unsigned long long nz = __ballot(ei[1 + 2 * t] != 0);
    unsigned e = (xh[2 * t] >> 7) & 0xFF;
    unsigned long long ok = __ballot(e >= 90 && e <= 142);
    if (t == 0) {
        flags[0] = (nz == 0ull) ? 1 : 0;
        flags[1] = (__popcll(ok) >= 48) ? 1 : 0;
    }
}

__global__ void count_kernel(const int* __restrict__ idx, const int* __restrict__ flags,
                             int* __restrict__ deg, int E) {
    int e = blockIdx.x * 256 + threadIdx.x;
    if (e >= E) return;
    int d = flags[0] ? idx[2 * (E + e)] : idx[E + e];
    d = min(max(d, 0), NNODES - 1);
    atomicAdd(&deg[d], 1);
}

// hierarchical exclusive scan of deg -> offs, plus dis = rsqrt(deg+1)
__global__ void reduce_kernel(const int* __restrict__ deg, int* __restrict__ bsum, int n) {
    __shared__ int l[256];
    int i = blockIdx.x * 256 + threadIdx.x;
    l[threadIdx.x] = (i < n) ? deg[i] : 0;
    __syncthreads();
    for (int o = 128; o > 0; o >>= 1) {
        if (threadIdx.x < o) l[threadIdx.x] += l[threadIdx.x + o];
        __syncthreads();
    }
    if (threadIdx.x == 0) bsum[blockIdx.x] = l[0];
}

__global__ void scanb_kernel(const int* __restrict__ bsum, int nb,
                             int* __restrict__ boff, int* __restrict__ offs_last) {
    __shared__ int l[256];                     // nb <= 256, single block
    int v = (threadIdx.x < nb) ? bsum[threadIdx.x] : 0;
    l[threadIdx.x] = v;
    __syncthreads();
    for (int o = 1; o < 256; o <<= 1) {
        int t = (threadIdx.x >= o) ? l[threadIdx.x - o] : 0;
        __syncthreads();
        l[threadIdx.x] += t;
        __syncthreads();
    }
    if (threadIdx.x < nb) boff[threadIdx.x] = l[threadIdx.x] - v;   // exclusive
    if (threadIdx.x == 255) *offs_last = l[255];
}

__global__ void local_scan_kernel(const int* __restrict__ deg, const int* __restrict__ boff,
                                  int* __restrict__ offs, float* __restrict__ dis, int n) {
    __shared__ int l[256];
    int i = blockIdx.x * 256 + threadIdx.x;
    int v = (i < n) ? deg[i] : 0;
    l[threadIdx.x] = v;
    __syncthreads();
    for (int o = 1; o < 256; o <<= 1) {
        int t = (threadIdx.x >= o) ? l[threadIdx.x - o] : 0;
        __syncthreads();
        l[threadIdx.x] += t;
        __syncthreads();
    }
    if (i < n) {
        offs[i] = boff[blockIdx.x] + l[threadIdx.x] - v;
        dis[i]  = rsqrtf((float)v + 1.0f);
    }
}

__global__ void fill_kernel(const int* __restrict__ idx, const int* __restrict__ flags,
                            const int* __restrict__ offs, int* __restrict__ cursor,
                            int* __restrict__ csr, int E) {
    int e = blockIdx.x * 256 + threadIdx.x;
    if (e >= E) return;
    int s, d;
    if (flags[0]) { s = idx[2 * e]; d = idx[2 * (E + e)]; }
    else          { s = idx[e];     d = idx[E + e]; }
    s = min(max(s, 0), NNODES - 1);
    d = min(max(d, 0), NNODES - 1);
    int p = atomicAdd(&cursor[d], 1);
    csr[offs[d] + p] = s;
}

// ---------------- weight repack: W[K,N] -> MFMA B-fragment order (bf16) ----------------
// Pack index: ((kt*(N/16)+nt)*64 + lane)*8 + j  holds  W[kt*32 + (lane>>4)*8 + j][nt*16 + (lane&15)]
__global__ void repack_kernel(const void* __restrict__ Wv, const int* __restrict__ flags,
                              __hip_bfloat16* __restrict__ P, int K, int N) {
    int ntiles = N / 16;
    int nt = blockIdx.x % ntiles;
    int kt = blockIdx.x / ntiles;
    int lane = threadIdx.x;
    int quad = lane >> 4, l16 = lane & 15;
    size_t pbase = ((size_t)blockIdx.x * 64 + lane) * 8;
    int k0 = kt * 32 + quad * 8;
    int col = nt * 16 + l16;
    bool bf = flags[1] != 0;
    for (int j = 0; j < 8; ++j) {
        size_t src = (size_t)(k0 + j) * N + col;
        P[pbase + j] = bf ? ((const __hip_bfloat16*)Wv)[src]
                          : (__hip_bfloat16)((const float*)Wv)[src];
    }
}

// ---------------- GEMM: C[M,256] = A[M,K] @ Bpack (+bias) ----------------
// Barrier-free main loop. Block = 2 waves (128 threads); each wave owns
// 32 rows x 256 cols (acc0[16]+acc1[16] f32_4; B fragment shared across the
// two 16-row halves). B-pack is small (128-256 KB) and L2-hot, so B fragments
// load STRAIGHT from global into registers -- no LDS staging, no __syncthreads,
// no vmcnt(0) drains in the K-loop (the old version's 7% MfmaUtil stall).
// A (the only HBM stream) uses an explicit depth-4 rotating prefetch.
// LDS is used only as a per-wave C-staging bounce for full-line bf16 stores.
template<int K>
__global__ __launch_bounds__(128, 2)
void gemm_kernel(const void* __restrict__ Av,
                 const __hip_bfloat16* __restrict__ Bp,
                 const void* __restrict__ biasv,   // nullable, dtype per flags[1]
                 void* __restrict__ Cv,
                 const int* __restrict__ flags, int amode, int cmode,
                 int M) {
    constexpr int N = 256;
    constexpr int NKT = K / 32;
    constexpr int PF  = 4;                       // A-prefetch depth (divides NKT)
    __shared__ __align__(16) __hip_bfloat16 cstage[2 * 32 * CSTRIDE];

    const int wave = threadIdx.x >> 6;
    const int lane = threadIdx.x & 63;
    const int quad = lane >> 4;
    const int l16  = lane & 15;
    const int row0 = blockIdx.x * 64 + wave * 32;   // this wave's first row
    const bool active0 = row0 < M;                  // rows row0..row0+15  (M%16==0)
    const bool active1 = row0 + 16 < M;             // rows row0+16..row0+31
    const bool bf  = flags[1] != 0;
    const bool abf = amode || bf;
    const bool cbf = cmode || bf;

    f32_4 acc0[16] = {};
    f32_4 acc1[16] = {};

    // A fragment loader: half h (0/1), k-tile kt -> lane holds
    // A[row0+h*16+l16][kt*32+quad*8 .. +8)
    auto loadA = [&](int h, int kt) -> bf16_8 {
        bf16_8 r = {};
        bool act = h ? active1 : active0;
        if (!act) return r;
        size_t ab = (size_t)(row0 + h * 16 + l16) * K + (size_t)kt * 32 + quad * 8;
        if (abf) {
            r = *(const bf16_8*)((const __hip_bfloat16*)Av + ab);
        } else {
            const float* Af = (const float*)Av + ab;
            f32_4 lo = *(const f32_4*)Af;
            f32_4 hi = *(const f32_4*)(Af + 4);
            #pragma unroll
            for (int j = 0; j < 4; ++j) { r[j] = (__bf16)lo[j]; r[j + 4] = (__bf16)hi[j]; }
        }
        return r;
    };

    bf16_8 a0p[PF], a1p[PF];
    #pragma unroll
    for (int i = 0; i < PF; ++i) { a0p[i] = loadA(0, i); a1p[i] = loadA(1, i); }

    #pragma unroll
    for (int kt = 0; kt < NKT; ++kt) {
        const int slot = kt % PF;                   // compile-time (full unroll)
        bf16_8 a0 = a0p[slot], a1 = a1p[slot];
        if (kt + PF < NKT) {                        // rotate in the next A tile
            a0p[slot] = loadA(0, kt + PF);
            a1p[slot] = loadA(1, kt + PF);
        }
        const __hip_bfloat16* bbase = Bp + (size_t)kt * 8192 + lane * 8;
        #pragma unroll
        for (int ct = 0; ct < 16; ++ct) {
            bf16_8 b = *(const bf16_8*)(bbase + ct * 512);
            acc0[ct] = __builtin_amdgcn_mfma_f32_16x16x32_bf16(a0, b, acc0[ct], 0, 0, 0);
            acc1[ct] = __builtin_amdgcn_mfma_f32_16x16x32_bf16(a1, b, acc1[ct], 0, 0, 0);
        }
    }

    if (cbf) {
        // bf16 output: per-wave LDS bounce, then full-line 16B stores
        __hip_bfloat16* cs = cstage + wave * 32 * CSTRIDE;
        #pragma unroll
        for (int ct = 0; ct < 16; ++ct) {
            int col = ct * 16 + l16;
            float bv = 0.0f;
            if (biasv) bv = bf ? (float)((const __hip_bfloat16*)biasv)[col]
                               : ((const float*)biasv)[col];
            #pragma unroll
            for (int rr = 0; rr < 4; ++rr) {
                int rl = quad * 4 + rr;
                cs[rl * CSTRIDE + col]        = (__hip_bfloat16)(acc0[ct][rr] + bv);
                cs[(16 + rl) * CSTRIDE + col] = (__hip_bfloat16)(acc1[ct][rr] + bv);
            }
        }
        __syncthreads();                            // once per kernel (cross-lane LDS vis)
        const int rloc = lane >> 5;                 // 0..1
        const int q16  = lane & 31;                 // 16B chunk within a 512B row
        #pragma unroll
        for (int pass = 0; pass < 16; ++pass) {
            int r = pass * 2 + rloc;
            int row = row0 + r;
            if (row < M) {
                bf16_8 v = *(const bf16_8*)(cs + r * CSTRIDE + q16 * 8);
                *(bf16_8*)((__hip_bfloat16*)Cv + (size_t)row * N + q16 * 8) = v;
            }
        }
    } else {
        // fp32 output (cold path): direct scalar stores
        #pragma unroll
        for (int ct = 0; ct < 16; ++ct) {
            int col = ct * 16 + l16;
            float bv = 0.0f;
            if (biasv) bv = bf ? (float)((const __hip_bfloat16*)biasv)[col]
                               : ((const float*)biasv)[col];
            #pragma unroll
            for (int rr = 0; rr < 4; ++rr) {
                int row = row0 + quad * 4 + rr;
                if (active0)
                    ((float*)Cv)[(size_t)row * N + col] = acc0[ct][rr] + bv;
                if (active1)
                    ((float*)Cv)[(size_t)(row + 16) * N + col] = acc1[ct][rr] + bv;
            }
        }
    }
}

// ---------------- aggregation: out[n] = dis[n]*sum dis[s]*h[s] + dis[n]^2*h[n] + b ----------------
// One wave per node. Half-wave (32 lanes x 16B = full 512B row) per edge slot,
// 2 slots/wave, x2 unroll => 4 gathers in flight. shfl_xor(32) combines halves.
__device__ inline void acc_row(f32_4& a0, f32_4& a1, float w, bf16_8 r) {
    a0[0] += w * (float)r[0]; a0[1] += w * (float)r[1];
    a0[2] += w * (float)r[2]; a0[3] += w * (float)r[3];
    a1[0] += w * (float)r[4]; a1[1] += w * (float)r[5];
    a1[2] += w * (float)r[6]; a1[3] += w * (float)r[7];
}

__global__ __launch_bounds__(256)
void agg_kernel(const __hip_bfloat16* __restrict__ h,
                const int* __restrict__ csr,
                const int* __restrict__ offs,
                const float* __restrict__ dis,
                const void* __restrict__ biasv,
                const int* __restrict__ flags,
                __hip_bfloat16* __restrict__ out,
                int relu) {
    const int wave = threadIdx.x >> 6;
    const int lane = threadIdx.x & 63;
    const int n = blockIdx.x * 4 + wave;
    if (n >= NNODES) return;
    const int half = lane >> 5;
    const int l32  = lane & 31;

    const float dn = dis[n];
    const int beg = offs[n], end = offs[n + 1];
    f32_4 a0 = {}, a1 = {};                    // features [8*l32, 8*l32+8)

    int j = beg + half;
    for (; j + 2 < end; j += 4) {              // 2 edges per half-wave per iter
        int sa = csr[j], sb = csr[j + 2];
        bf16_8 ra = *(const bf16_8*)(h + (size_t)sa * HIDDIM + l32 * 8);
        bf16_8 rb = *(const bf16_8*)(h + (size_t)sb * HIDDIM + l32 * 8);
        float wa = dis[sa], wb = dis[sb];
        acc_row(a0, a1, wa, ra);
        acc_row(a0, a1, wb, rb);
    }
    if (j < end) {
        int sa = csr[j];
        bf16_8 ra = *(const bf16_8*)(h + (size_t)sa * HIDDIM + l32 * 8);
        acc_row(a0, a1, dis[sa], ra);
    }

    // combine the two half-wave partials (features match across halves)
    #pragma unroll
    for (int k = 0; k < 4; ++k) {
        a0[k] += __shfl_xor(a0[k], 32);
        a1[k] += __shfl_xor(a1[k], 32);
    }

    // self-loop + bias
    bf16_8 rn = *(const bf16_8*)(h + (size_t)n * HIDDIM + l32 * 8);
    float bv[8];
    if (flags[1]) {
        bf16_8 bb = ((const bf16_8*)biasv)[l32];
        #pragma unroll
        for (int k = 0; k < 8; ++k) bv[k] = (float)bb[k];
    } else {
        f32_4 blo = *((const f32_4*)biasv + 2 * l32);
        f32_4 bhi = *((const f32_4*)biasv + 2 * l32 + 1);
        #pragma unroll
        for (int k = 0; k < 4; ++k) { bv[k] = blo[k]; bv[k + 4] = bhi[k]; }
    }
    const float dn2 = dn * dn;
    float v[8];
    #pragma unroll
    for (int k = 0; k < 4; ++k) {
        v[k]     = dn * a0[k] + dn2 * (float)rn[k]     + bv[k];
        v[k + 4] = dn * a1[k] + dn2 * (float)rn[k + 4] + bv[k + 4];
    }
    if (relu) {
        #pragma unroll
        for (int k = 0; k < 8; ++k) v[k] = fmaxf(v[k], 0.0f);
    }
    if (half == 0) {
        bf16_8 o;
        #pragma unroll
        for (int k = 0; k < 8; ++k) o[k] = (__bf16)v[k];
        *(bf16_8*)(out + (size_t)n * HIDDIM + l32 * 8) = o;
    }
}

// ---------------- launch ----------------

extern "C" void kernel_launch(void* const* d_in, const int* in_sizes, int n_in,
                              void* d_out, int out_size, void* d_ws, size_t ws_size,
                              hipStream_t stream) {
    const int M = NNODES, E = NEDGES;
    const void* x  = d_in[0];
    const int*  ei = (const int*)d_in[1];
    const void* W1 = d_in[2];
    const void* b1 = d_in[3];
    const void* W2 = d_in[4];
    const void* b2 = d_in[5];
    const void* Wp = d_in[6];
    const void* bp = d_in[7];

    // ws layout (~4.5 MB). Big ping/pong buffers live in d_out and the x input
    // buffer (harness restores d_in before every launch; x is dead after gemm1).
    char* w = (char*)d_ws;
    size_t off = 0;
    auto alloc = [&](size_t bytes) -> void* {
        void* p = w + off;
        off += (bytes + 255) & ~(size_t)255;
        return p;
    };
    int*   deg    = (int*)alloc((size_t)M * 4);
    int*   cursor = (int*)alloc((size_t)M * 4);
    int*   offs   = (int*)alloc((size_t)(M + 1) * 4);
    float* dis    = (float*)alloc((size_t)M * 4);
    int*   flags  = (int*)alloc(256);
    int*   bsum   = (int*)alloc(256 * 4);
    int*   boff   = (int*)alloc(256 * 4);
    int*   csr    = (int*)alloc((size_t)E * 4);
    __hip_bfloat16* W1p = (__hip_bfloat16*)alloc((size_t)INDIM * HIDDIM * 2);
    __hip_bfloat16* W2p = (__hip_bfloat16*)alloc((size_t)HIDDIM * HIDDIM * 2);
    __hip_bfloat16* Wpp = (__hip_bfloat16*)alloc((size_t)HIDDIM * HIDDIM * 2);
    if (ws_size < off) return;

    __hip_bfloat16* h  = (__hip_bfloat16*)d_out;   // ping
    __hip_bfloat16* ha = (__hip_bfloat16*)d_in[0]; // pong (x buffer)

    const int nb = (M + 255) / 256;                // 196 scan blocks

    // CSR build + dtype detection
    zero_kernel<<<nb, 256, 0, stream>>>(deg, M);
    zero_kernel<<<nb, 256, 0, stream>>>(cursor, M);
    detect_kernel<<<1, 64, 0, stream>>>(ei, (const unsigned short*)x, flags);
    count_kernel<<<(E + 255) / 256, 256, 0, stream>>>(ei, flags, deg, E);
    reduce_kernel<<<nb, 256, 0, stream>>>(deg, bsum, M);
    scanb_kernel<<<1, 256, 0, stream>>>(bsum, nb, boff, &offs[M]);
    local_scan_kernel<<<nb, 256, 0, stream>>>(deg, boff, offs, dis, M);
    fill_kernel<<<(E + 255) / 256, 256, 0, stream>>>(ei, flags, offs, cursor, csr, E);

    // weight repack (dtype-aware)
    repack_kernel<<<(INDIM / 32) * (HIDDIM / 16), 64, 0, stream>>>(W1, flags, W1p, INDIM, HIDDIM);
    repack_kernel<<<(HIDDIM / 32) * (HIDDIM / 16), 64, 0, stream>>>(W2, flags, W2p, HIDDIM, HIDDIM);
    repack_kernel<<<(HIDDIM / 32) * (HIDDIM / 16), 64, 0, stream>>>(Wp, flags, Wpp, HIDDIM, HIDDIM);

    const int ggrid = (M + 63) / 64;               // 782 blocks, 64 rows (2 waves x 32)
    const int agrid = (M + 3) / 4;

    // layer 1: h = x @ W1 ; ha = relu(agg(h) + b1)
    gemm_kernel<INDIM><<<ggrid, 128, 0, stream>>>(x, W1p, nullptr, h, flags, 0, 1, M);
    agg_kernel<<<agrid, 256, 0, stream>>>(h, csr, offs, dis, b1, flags, ha, 1);

    // layer 2: h = ha @ W2 ; ha = agg(h) + b2
    gemm_kernel<HIDDIM><<<ggrid, 128, 0, stream>>>(ha, W2p, nullptr, h, flags, 1, 1, M);
    agg_kernel<<<agrid, 256, 0, stream>>>(h, csr, offs, dis, b2, flags, ha, 0);

    // projection: out = ha @ Wp + bp   (output dtype follows detected mode)
    gemm_kernel<HIDDIM><<<ggrid, 128, 0, stream>>>(ha, Wpp, bp, d_out, flags, 1, 0, M);
}

// Round 2
// 471.813 us; speedup vs baseline: 1.0630x; 1.0630x over previous
//
#include <hip/hip_runtime.h>
#include <hip/hip_bf16.h>

typedef __bf16 bf16_8 __attribute__((ext_vector_type(8)));
typedef float  f32_4  __attribute__((ext_vector_type(4)));

#define NNODES 50000
#define NEDGES 800000
#define INDIM  512
#define HIDDIM 256
#define CSTRIDE 264   // elems; 264*2=528 B rows (16B-aligned), breaks pow2 bank stride

// async global->LDS, 16 B per lane (LDS dest = uniform base + lane*16)
__device__ inline void gload_lds16(const __hip_bfloat16* g, __hip_bfloat16* l) {
    __builtin_amdgcn_global_load_lds(
        (const __attribute__((address_space(1))) void*)g,
        (__attribute__((address_space(3))) void*)l, 16, 0, 0);
}

// ---------------- small utility kernels ----------------

__global__ void zero_kernel(int* p, int n) {
    int i = blockIdx.x * 256 + threadIdx.x;
    if (i < n) p[i] = 0;
}

// flags[0]: edge_index is int64 (odd int32 words all zero)
// flags[1]: float data is bf16 (even halfwords of x look like sane bf16 exponents)
__global__ void detect_kernel(const int* __restrict__ ei,
                              const unsigned short* __restrict__ xh,
                              int* __restrict__ flags) {
    int t = threadIdx.x;                       // 64 threads
    unsigned long long nz = __ballot(ei[1 + 2 * t] != 0);
    unsigned e = (xh[2 * t] >> 7) & 0xFF;
    unsigned long long ok = __ballot(e >= 90 && e <= 142);
    if (t == 0) {
        flags[0] = (nz == 0ull) ? 1 : 0;
        flags[1] = (__popcll(ok) >= 48) ? 1 : 0;
    }
}

__global__ void count_kernel(const int* __restrict__ idx, const int* __restrict__ flags,
                             int* __restrict__ deg, int E) {
    int e = blockIdx.x * 256 + threadIdx.x;
    if (e >= E) return;
    int d = flags[0] ? idx[2 * (E + e)] : idx[E + e];
    d = min(max(d, 0), NNODES - 1);
    atomicAdd(&deg[d], 1);
}

// hierarchical exclusive scan of deg -> offs, plus dis = rsqrt(deg+1)
__global__ void reduce_kernel(const int* __restrict__ deg, int* __restrict__ bsum, int n) {
    __shared__ int l[256];
    int i = blockIdx.x * 256 + threadIdx.x;
    l[threadIdx.x] = (i < n) ? deg[i] : 0;
    __syncthreads();
    for (int o = 128; o > 0; o >>= 1) {
        if (threadIdx.x < o) l[threadIdx.x] += l[threadIdx.x + o];
        __syncthreads();
    }
    if (threadIdx.x == 0) bsum[blockIdx.x] = l[0];
}

__global__ void scanb_kernel(const int* __restrict__ bsum, int nb,
                             int* __restrict__ boff, int* __restrict__ offs_last) {
    __shared__ int l[256];                     // nb <= 256, single block
    int v = (threadIdx.x < nb) ? bsum[threadIdx.x] : 0;
    l[threadIdx.x] = v;
    __syncthreads();
    for (int o = 1; o < 256; o <<= 1) {
        int t = (threadIdx.x >= o) ? l[threadIdx.x - o] : 0;
        __syncthreads();
        l[threadIdx.x] += t;
        __syncthreads();
    }
    if (threadIdx.x < nb) boff[threadIdx.x] = l[threadIdx.x] - v;   // exclusive
    if (threadIdx.x == 255) *offs_last = l[255];
}

__global__ void local_scan_kernel(const int* __restrict__ deg, const int* __restrict__ boff,
                                  int* __restrict__ offs, float* __restrict__ dis, int n) {
    __shared__ int l[256];
    int i = blockIdx.x * 256 + threadIdx.x;
    int v = (i < n) ? deg[i] : 0;
    l[threadIdx.x] = v;
    __syncthreads();
    for (int o = 1; o < 256; o <<= 1) {
        int t = (threadIdx.x >= o) ? l[threadIdx.x - o] : 0;
        __syncthreads();
        l[threadIdx.x] += t;
        __syncthreads();
    }
    if (i < n) {
        offs[i] = boff[blockIdx.x] + l[threadIdx.x] - v;
        dis[i]  = rsqrtf((float)v + 1.0f);
    }
}

__global__ void fill_kernel(const int* __restrict__ idx, const int* __restrict__ flags,
                            const int* __restrict__ offs, int* __restrict__ cursor,
                            int* __restrict__ csr, int E) {
    int e = blockIdx.x * 256 + threadIdx.x;
    if (e >= E) return;
    int s, d;
    if (flags[0]) { s = idx[2 * e]; d = idx[2 * (E + e)]; }
    else          { s = idx[e];     d = idx[E + e]; }
    s = min(max(s, 0), NNODES - 1);
    d = min(max(d, 0), NNODES - 1);
    int p = atomicAdd(&cursor[d], 1);
    csr[offs[d] + p] = s;
}

// ---------------- weight repack: W[K,N] -> MFMA B-fragment order (bf16) ----------------
// Pack index: ((kt*(N/16)+nt)*64 + lane)*8 + j  holds  W[kt*32 + (lane>>4)*8 + j][nt*16 + (lane&15)]
__global__ void repack_kernel(const void* __restrict__ Wv, const int* __restrict__ flags,
                              __hip_bfloat16* __restrict__ P, int K, int N) {
    int ntiles = N / 16;
    int nt = blockIdx.x % ntiles;
    int kt = blockIdx.x / ntiles;
    int lane = threadIdx.x;
    int quad = lane >> 4, l16 = lane & 15;
    size_t pbase = ((size_t)blockIdx.x * 64 + lane) * 8;
    int k0 = kt * 32 + quad * 8;
    int col = nt * 16 + l16;
    bool bf = flags[1] != 0;
    for (int j = 0; j < 8; ++j) {
        size_t src = (size_t)(k0 + j) * N + col;
        P[pbase + j] = bf ? ((const __hip_bfloat16*)Wv)[src]
                          : (__hip_bfloat16)((const float*)Wv)[src];
    }
}

// ---------------- GEMM: C[M,256] = A[M,K] @ Bpack (+bias) ----------------
// Block = 4 waves x 32 rows = 128 rows. K processed in phases of 4 k-tiles
// (128 K-elems): the 64 KB B phase-slab is staged into LDS via global_load_lds
// (64 chunks x 1 KB), with ALL of this phase's A fragments batch-issued first
// so ONE __syncthreads() drain covers both streams. The inner loop is then
// pure conflict-free ds_read_b128 + MFMA with zero vmem waits (one drain per
// 64 MFMAs/wave). 64 KB LDS + <=256 VGPR => 2 blocks/CU => all 391 blocks
// co-resident: stage-drain of one block overlaps compute of the other.
template<int K>
__global__ __launch_bounds__(256, 2)
void gemm_kernel(const void* __restrict__ Av,
                 const __hip_bfloat16* __restrict__ Bp,
                 const void* __restrict__ biasv,   // nullable, dtype per flags[1]
                 void* __restrict__ Cv,
                 const int* __restrict__ flags, int amode, int cmode,
                 int M) {
    constexpr int N = 256;
    constexpr int PHKT   = 4;                 // k-tiles per phase (64 KB slab)
    constexpr int PHASES = K / (PHKT * 32);   // 4 (K=512) or 2 (K=256)
    __shared__ __align__(16) __hip_bfloat16 smem[PHKT * 8192];   // 64 KB

    const int wave = threadIdx.x >> 6;
    const int lane = threadIdx.x & 63;
    const int quad = lane >> 4;
    const int l16  = lane & 15;
    const int row0 = blockIdx.x * 128 + wave * 32;  // this wave's first row
    const bool active0 = row0 < M;                  // rows row0..+15   (M%16==0)
    const bool active1 = row0 + 16 < M;             // rows row0+16..+31
    const bool bf  = flags[1] != 0;
    const bool abf = amode || bf;
    const bool cbf = cmode || bf;

    f32_4 acc0[16] = {};
    f32_4 acc1[16] = {};

    // A fragment: half h (0/1), k-tile kt -> lane holds A[row0+h*16+l16][kt*32+quad*8 ..+8)
    auto loadA = [&](int h, int kt) -> bf16_8 {
        bf16_8 r = {};
        bool act = h ? active1 : active0;
        if (!act) return r;
        size_t ab = (size_t)(row0 + h * 16 + l16) * K + (size_t)kt * 32 + quad * 8;
        if (abf) {
            r = *(const bf16_8*)((const __hip_bfloat16*)Av + ab);
        } else {
            const float* Af = (const float*)Av + ab;
            f32_4 lo = *(const f32_4*)Af;
            f32_4 hi = *(const f32_4*)(Af + 4);
            #pragma unroll
            for (int j = 0; j < 4; ++j) { r[j] = (__bf16)lo[j]; r[j + 4] = (__bf16)hi[j]; }
        }
        return r;
    };

    #pragma unroll
    for (int ph = 0; ph < PHASES; ++ph) {
        // (1) batch-issue this phase's A fragments (HBM stream, max lead time)
        bf16_8 a0[PHKT], a1[PHKT];
        #pragma unroll
        for (int k2 = 0; k2 < PHKT; ++k2) {
            a0[k2] = loadA(0, ph * PHKT + k2);
            a1[k2] = loadA(1, ph * PHKT + k2);
        }
        // (2) previous slab fully consumed before overwrite
        if (ph > 0) __syncthreads();
        // (3) stage 64 KB B slab: 64 chunks x 1 KB, wave-strided
        const __hip_bfloat16* slab = Bp + (size_t)ph * (PHKT * 8192);
        #pragma unroll
        for (int i = 0; i < PHKT * 4; ++i) {
            int ch = i * 4 + wave;
            gload_lds16(slab + ch * 512 + lane * 8, smem + ch * 512);
        }
        // (4) single drain for A + slab
        __syncthreads();
        // (5) pure LDS->MFMA compute: 4 kt x (16 ds_read_b128 + 32 MFMA)
        #pragma unroll
        for (int k2 = 0; k2 < PHKT; ++k2) {
            const __hip_bfloat16* bb = smem + k2 * 8192 + lane * 8;
            #pragma unroll
            for (int ct = 0; ct < 16; ++ct) {
                bf16_8 b = *(const bf16_8*)(bb + ct * 512);
                acc0[ct] = __builtin_amdgcn_mfma_f32_16x16x32_bf16(a0[k2], b, acc0[ct], 0, 0, 0);
                acc1[ct] = __builtin_amdgcn_mfma_f32_16x16x32_bf16(a1[k2], b, acc1[ct], 0, 0, 0);
            }
        }
    }

    __syncthreads();                          // LDS reuse: B slab -> C bounce
    if (cbf) {
        // wave-local 16-row bounce (no further block barriers), full-line stores
        __hip_bfloat16* cs = smem + wave * 16 * CSTRIDE;     // 16.9 KB/wave
        #pragma unroll
        for (int pass = 0; pass < 2; ++pass) {
            const int rowg = row0 + pass * 16;
            #pragma unroll
            for (int ct = 0; ct < 16; ++ct) {
                int col = ct * 16 + l16;
                float bv = 0.0f;
                if (biasv) bv = bf ? (float)((const __hip_bfloat16*)biasv)[col]
                                   : ((const float*)biasv)[col];
                #pragma unroll
                for (int rr = 0; rr < 4; ++rr) {
                    float v = (pass ? acc1[ct][rr] : acc0[ct][rr]) + bv;
                    cs[(quad * 4 + rr) * CSTRIDE + col] = (__hip_bfloat16)v;
                }
            }
            // wave-local read-back (compiler orders ds ops via lgkmcnt)
            const int r  = lane >> 2;          // 16 rows, 4 threads/row
            const int qc = lane & 3;           // 128 B each
            if (rowg + r < M) {
                __hip_bfloat16* crow = (__hip_bfloat16*)Cv + (size_t)(rowg + r) * N;
                #pragma unroll
                for (int j = 0; j < 8; ++j) {
                    int col = qc * 64 + j * 8;
                    *(bf16_8*)(crow + col) = *(const bf16_8*)(cs + r * CSTRIDE + col);
                }
            }
        }
    } else {
        // fp32 output (cold path): direct scalar stores
        #pragma unroll
        for (int ct = 0; ct < 16; ++ct) {
            int col = ct * 16 + l16;
            float bv = 0.0f;
            if (biasv) bv = bf ? (float)((const __hip_bfloat16*)biasv)[col]
                               : ((const float*)biasv)[col];
            #pragma unroll
            for (int rr = 0; rr < 4; ++rr) {
                int row = row0 + quad * 4 + rr;
                if (active0)
                    ((float*)Cv)[(size_t)row * N + col] = acc0[ct][rr] + bv;
                if (active1)
                    ((float*)Cv)[(size_t)(row + 16) * N + col] = acc1[ct][rr] + bv;
            }
        }
    }
}

// ---------------- aggregation: out[n] = dis[n]*sum dis[s]*h[s] + dis[n]^2*h[n] + b ----------------
// One wave per node. Half-wave (32 lanes x 16B = full 512B row) per edge slot,
// 2 slots/wave, x2 unroll => 4 gathers in flight. shfl_xor(32) combines halves.
__device__ inline void acc_row(f32_4& a0, f32_4& a1, float w, bf16_8 r) {
    a0[0] += w * (float)r[0]; a0[1] += w * (float)r[1];
    a0[2] += w * (float)r[2]; a0[3] += w * (float)r[3];
    a1[0] += w * (float)r[4]; a1[1] += w * (float)r[5];
    a1[2] += w * (float)r[6]; a1[3] += w * (float)r[7];
}

__global__ __launch_bounds__(256)
void agg_kernel(const __hip_bfloat16* __restrict__ h,
                const int* __restrict__ csr,
                const int* __restrict__ offs,
                const float* __restrict__ dis,
                const void* __restrict__ biasv,
                const int* __restrict__ flags,
                __hip_bfloat16* __restrict__ out,
                int relu) {
    const int wave = threadIdx.x >> 6;
    const int lane = threadIdx.x & 63;
    const int n = blockIdx.x * 4 + wave;
    if (n >= NNODES) return;
    const int half = lane >> 5;
    const int l32  = lane & 31;

    const float dn = dis[n];
    const int beg = offs[n], end = offs[n + 1];
    f32_4 a0 = {}, a1 = {};                    // features [8*l32, 8*l32+8)

    int j = beg + half;
    for (; j + 2 < end; j += 4) {              // 2 edges per half-wave per iter
        int sa = csr[j], sb = csr[j + 2];
        bf16_8 ra = *(const bf16_8*)(h + (size_t)sa * HIDDIM + l32 * 8);
        bf16_8 rb = *(const bf16_8*)(h + (size_t)sb * HIDDIM + l32 * 8);
        float wa = dis[sa], wb = dis[sb];
        acc_row(a0, a1, wa, ra);
        acc_row(a0, a1, wb, rb);
    }
    if (j < end) {
        int sa = csr[j];
        bf16_8 ra = *(const bf16_8*)(h + (size_t)sa * HIDDIM + l32 * 8);
        acc_row(a0, a1, dis[sa], ra);
    }

    // combine the two half-wave partials (features match across halves)
    #pragma unroll
    for (int k = 0; k < 4; ++k) {
        a0[k] += __shfl_xor(a0[k], 32);
        a1[k] += __shfl_xor(a1[k], 32);
    }

    // self-loop + bias
    bf16_8 rn = *(const bf16_8*)(h + (size_t)n * HIDDIM + l32 * 8);
    float bv[8];
    if (flags[1]) {
        bf16_8 bb = ((const bf16_8*)biasv)[l32];
        #pragma unroll
        for (int k = 0; k < 8; ++k) bv[k] = (float)bb[k];
    } else {
        f32_4 blo = *((const f32_4*)biasv + 2 * l32);
        f32_4 bhi = *((const f32_4*)biasv + 2 * l32 + 1);
        #pragma unroll
        for (int k = 0; k < 4; ++k) { bv[k] = blo[k]; bv[k + 4] = bhi[k]; }
    }
    const float dn2 = dn * dn;
    float v[8];
    #pragma unroll
    for (int k = 0; k < 4; ++k) {
        v[k]     = dn * a0[k] + dn2 * (float)rn[k]     + bv[k];
        v[k + 4] = dn * a1[k] + dn2 * (float)rn[k + 4] + bv[k + 4];
    }
    if (relu) {
        #pragma unroll
        for (int k = 0; k < 8; ++k) v[k] = fmaxf(v[k], 0.0f);
    }
    if (half == 0) {
        bf16_8 o;
        #pragma unroll
        for (int k = 0; k < 8; ++k) o[k] = (__bf16)v[k];
        *(bf16_8*)(out + (size_t)n * HIDDIM + l32 * 8) = o;
    }
}

// ---------------- launch ----------------

extern "C" void kernel_launch(void* const* d_in, const int* in_sizes, int n_in,
                              void* d_out, int out_size, void* d_ws, size_t ws_size,
                              hipStream_t stream) {
    const int M = NNODES, E = NEDGES;
    const void* x  = d_in[0];
    const int*  ei = (const int*)d_in[1];
    const void* W1 = d_in[2];
    const void* b1 = d_in[3];
    const void* W2 = d_in[4];
    const void* b2 = d_in[5];
    const void* Wp = d_in[6];
    const void* bp = d_in[7];

    // ws layout (~4.5 MB). Big ping/pong buffers live in d_out and the x input
    // buffer (harness restores d_in before every launch; x is dead after gemm1).
    char* w = (char*)d_ws;
    size_t off = 0;
    auto alloc = [&](size_t bytes) -> void* {
        void* p = w + off;
        off += (bytes + 255) & ~(size_t)255;
        return p;
    };
    int*   deg    = (int*)alloc((size_t)M * 4);
    int*   cursor = (int*)alloc((size_t)M * 4);
    int*   offs   = (int*)alloc((size_t)(M + 1) * 4);
    float* dis    = (float*)alloc((size_t)M * 4);
    int*   flags  = (int*)alloc(256);
    int*   bsum   = (int*)alloc(256 * 4);
    int*   boff   = (int*)alloc(256 * 4);
    int*   csr    = (int*)alloc((size_t)E * 4);
    __hip_bfloat16* W1p = (__hip_bfloat16*)alloc((size_t)INDIM * HIDDIM * 2);
    __hip_bfloat16* W2p = (__hip_bfloat16*)alloc((size_t)HIDDIM * HIDDIM * 2);
    __hip_bfloat16* Wpp = (__hip_bfloat16*)alloc((size_t)HIDDIM * HIDDIM * 2);
    if (ws_size < off) return;

    __hip_bfloat16* h  = (__hip_bfloat16*)d_out;   // ping
    __hip_bfloat16* ha = (__hip_bfloat16*)d_in[0]; // pong (x buffer)

    const int nb = (M + 255) / 256;                // 196 scan blocks

    // CSR build + dtype detection
    zero_kernel<<<nb, 256, 0, stream>>>(deg, M);
    zero_kernel<<<nb, 256, 0, stream>>>(cursor, M);
    detect_kernel<<<1, 64, 0, stream>>>(ei, (const unsigned short*)x, flags);
    count_kernel<<<(E + 255) / 256, 256, 0, stream>>>(ei, flags, deg, E);
    reduce_kernel<<<nb, 256, 0, stream>>>(deg, bsum, M);
    scanb_kernel<<<1, 256, 0, stream>>>(bsum, nb, boff, &offs[M]);
    local_scan_kernel<<<nb, 256, 0, stream>>>(deg, boff, offs, dis, M);
    fill_kernel<<<(E + 255) / 256, 256, 0, stream>>>(ei, flags, offs, cursor, csr, E);

    // weight repack (dtype-aware)
    repack_kernel<<<(INDIM / 32) * (HIDDIM / 16), 64, 0, stream>>>(W1, flags, W1p, INDIM, HIDDIM);
    repack_kernel<<<(HIDDIM / 32) * (HIDDIM / 16), 64, 0, stream>>>(W2, flags, W2p, HIDDIM, HIDDIM);
    repack_kernel<<<(HIDDIM / 32) * (HIDDIM / 16), 64, 0, stream>>>(Wp, flags, Wpp, HIDDIM, HIDDIM);

    const int ggrid = (M + 127) / 128;             // 391 blocks, 128 rows each
    const int agrid = (M + 3) / 4;

    // layer 1: h = x @ W1 ; ha = relu(agg(h) + b1)
    gemm_kernel<INDIM><<<ggrid, 256, 0, stream>>>(x, W1p, nullptr, h, flags, 0, 1, M);
    agg_kernel<<<agrid, 256, 0, stream>>>(h, csr, offs, dis, b1, flags, ha, 1);

    // layer 2: h = ha @ W2 ; ha = agg(h) + b2
    gemm_kernel<HIDDIM><<<ggrid, 256, 0, stream>>>(ha, W2p, nullptr, h, flags, 1, 1, M);
    agg_kernel<<<agrid, 256, 0, stream>>>(h, csr, offs, dis, b2, flags, ha, 0);

    // projection: out = ha @ Wp + bp   (output dtype follows detected mode)
    gemm_kernel<HIDDIM><<<ggrid, 256, 0, stream>>>(ha, Wpp, bp, d_out, flags, 1, 0, M);
}